// Round 6
// baseline (434.943 us; speedup 1.0000x reference)
//
#include <hip/hip_runtime.h>
#include <hip/hip_bf16.h>

// Problem constants
#define B_     16384
#define TD     512     // T*D
#define HID    128
#define LAT    512     // N_TOKENS*CODE_DIM
#define NCODES 512
#define CDIM   64
#define EPS    1e-5f
#define DELTA  1.5f    // rescore margin; worst-case bf16 score error <= 0.64
#define QCAP   2048    // candidate queue capacity (expected ~410/block)

typedef __attribute__((ext_vector_type(8))) short bf16x8;
typedef __attribute__((ext_vector_type(4))) float f32x4;

// fp32 -> bf16 round-to-nearest-even (bit trick; no NaN inputs here)
static __device__ __forceinline__ unsigned short f2bf(float x) {
    unsigned int u = __float_as_uint(x);
    u = (u + 0x7FFFu + ((u >> 16) & 1u)) >> 16;
    return (unsigned short)u;
}

// order-preserving float->u32 (monotone; equal floats -> equal keys)
static __device__ __forceinline__ unsigned int fkey(float x) {
    unsigned int u = __float_as_uint(x);
    return u ^ (((unsigned int)((int)u >> 31)) | 0x80000000u);
}

// ---------------------------------------------------------------------------
// c2[c] = sum_d codebook[c][d]^2   (one wave per code)
// ---------------------------------------------------------------------------
__global__ void c2_kernel(const float* __restrict__ cb, float* __restrict__ c2) {
    int c = blockIdx.x;
    int d = threadIdx.x;
    float v = cb[c * CDIM + d];
    float s = v * v;
#pragma unroll
    for (int m = 32; m >= 1; m >>= 1) s += __shfl_xor(s, m, 64);
    if (d == 0) c2[c] = s;
}

// ---------------------------------------------------------------------------
// Weight/codebook prep: w1t[n=128][k=512], w2t[n=512][k=128] bf16 transposed;
// cbfrag = codebook in MFMA B-fragment order (verified in round 5):
// slot ((nt*2+kk)*64 + q*16 + l15)*8 + j  holds cb[nt*16+l15][kk*32+q*8+j].
// ---------------------------------------------------------------------------
__global__ void prep_kernel(const float* __restrict__ w1, const float* __restrict__ w2,
                            const float* __restrict__ cb,
                            unsigned short* __restrict__ w1t, unsigned short* __restrict__ w2t,
                            unsigned short* __restrict__ cbfrag) {
    int i = blockIdx.x * 256 + threadIdx.x;      // 0..163839
    if (i < 65536) {
        int n = i >> 9, k = i & 511;
        w1t[i] = f2bf(w1[k * HID + n]);
    } else if (i < 131072) {
        int j = i - 65536;
        int n = j >> 7, k = j & 127;
        w2t[j] = f2bf(w2[k * TD + n]);
    } else {
        int e    = i - 131072;                   // 0..32767
        int code = e >> 6, dim = e & 63;
        int nt = code >> 4, l15 = code & 15;
        int kk = dim >> 5, q = (dim & 31) >> 3, j = dim & 7;
        cbfrag[((nt * 2 + kk) * 64 + q * 16 + l15) * 8 + j] = f2bf(cb[code * CDIM + dim]);
    }
}

// ---------------------------------------------------------------------------
// fp32 GEMM (encoder): C[M,N] = A[M,K]@W[K,N] + bias (+ReLU / +LN per 64 cols)
// BM=64, BN=128, BK=32, 256 threads, 4x8 microtile.
// A from LDS (1 broadcast ds_read_b128 per 32 FMAs -> VALU-bound);
// W straight from global/L2 (coalesced 256B per wave-instruction).
// Per-output fmaf chains ascend k -> bit-identical GEMM results to round 2/4.
// ---------------------------------------------------------------------------
template<bool RELU, bool LN>
__launch_bounds__(256)
__global__ void gemm_f32(const float* __restrict__ A, const float* __restrict__ W,
                         const float* __restrict__ bias, float* __restrict__ C,
                         int N, int K) {
    __shared__ float As[32 * 68];    // As[k*68 + r], r=0..63

    const int tid = threadIdx.x;
    const int tx  = tid & 15;        // 8 cols each
    const int ty  = tid >> 4;        // 4 rows each
    const int n0  = blockIdx.x * 128;
    const int m0  = blockIdx.y * 64;

    float acc[4][8] = {};

    for (int k0 = 0; k0 < K; k0 += 32) {
        if (k0) __syncthreads();
        // stage A tile transposed: 64 rows x 32 k = 512 float4, 2 per thread
#pragma unroll
        for (int p = 0; p < 2; ++p) {
            int idx = p * 256 + tid;
            int r   = idx >> 3;                // 0..63
            int k4  = (idx & 7) * 4;
            float4 v = *(const float4*)&A[(size_t)(m0 + r) * K + k0 + k4];
            As[(k4 + 0) * 68 + r] = v.x;
            As[(k4 + 1) * 68 + r] = v.y;
            As[(k4 + 2) * 68 + r] = v.z;
            As[(k4 + 3) * 68 + r] = v.w;
        }
        __syncthreads();

#pragma unroll 8
        for (int k = 0; k < 32; ++k) {
            float4 a = *(const float4*)&As[k * 68 + ty * 4];   // broadcast, CF
            const float* wr = &W[(size_t)(k0 + k) * N + n0 + tx * 8];
            float4 wv0 = *(const float4*)wr;
            float4 wv1 = *(const float4*)(wr + 4);
            float av[4] = {a.x, a.y, a.z, a.w};
            float wv[8] = {wv0.x, wv0.y, wv0.z, wv0.w, wv1.x, wv1.y, wv1.z, wv1.w};
#pragma unroll
            for (int i = 0; i < 4; ++i)
#pragma unroll
                for (int j = 0; j < 8; ++j)
                    acc[i][j] = fmaf(av[i], wv[j], acc[i][j]);
        }
    }

    float bv[8];
#pragma unroll
    for (int j = 0; j < 8; ++j) bv[j] = bias[n0 + tx * 8 + j];

#pragma unroll
    for (int i = 0; i < 4; ++i) {
        float c[8];
#pragma unroll
        for (int j = 0; j < 8; ++j) {
            c[j] = acc[i][j] + bv[j];
            if (RELU) c[j] = fmaxf(c[j], 0.0f);
        }
        if (LN) {
            // token = 64 cols = 8 adjacent tx lanes (this thread holds 8 cols
            // of ONE token); reduce over shfl_xor 1,2,4 within the 8-group.
            float s = 0.0f, ss = 0.0f;
#pragma unroll
            for (int j = 0; j < 8; ++j) { s += c[j]; ss = fmaf(c[j], c[j], ss); }
#pragma unroll
            for (int m = 1; m <= 4; m <<= 1) {
                s  += __shfl_xor(s,  m, 64);
                ss += __shfl_xor(ss, m, 64);
            }
            float mean = s * (1.0f / 64.0f);
            float var  = ss * (1.0f / 64.0f) - mean * mean;
            float rstd = rsqrtf(var + EPS);
#pragma unroll
            for (int j = 0; j < 8; ++j) c[j] = (c[j] - mean) * rstd;
        }
        size_t row = (size_t)(m0 + ty * 4 + i);
        *(float4*)&C[row * N + n0 + tx * 8]     = make_float4(c[0], c[1], c[2], c[3]);
        *(float4*)&C[row * N + n0 + tx * 8 + 4] = make_float4(c[4], c[5], c[6], c[7]);
    }
}

// ---------------------------------------------------------------------------
// VQ: MFMA prefilter + queued exact fp32 rescore.
// 256 tokens/block (512 blocks), full 64KB bf16 codebook fragments in LDS.
// Wave w owns m-tiles w*4..w*4+3: per b-fragment ds_read -> 4 MFMAs (MFMA-bound).
// Pass 1: approx min per token. Pass 2: identical MFMAs; (t,c) with
// approx < min+DELTA pushed to LDS queue. Dense rescore phase: exact fp32
// dot per entry, committed via packed u64 atomicMin (tie -> lower index).
// Exactness: |approx-exact| <= 0.64 worst-case (||z||=8, max||c||~10.2),
// so true argmin always lands in the queue; overflow falls back inline.
// ---------------------------------------------------------------------------
__launch_bounds__(256)
__global__ void vq_mfma(const float* __restrict__ zln, const float* __restrict__ cb,
                        const unsigned short* __restrict__ cbfrag,
                        const float* __restrict__ c2, float* __restrict__ zq_ws,
                        float* __restrict__ zq_out, float* __restrict__ idx_out) {
    __shared__ unsigned short CBs[32768];            // 64 KB: all B-fragments
    __shared__ unsigned int   queue[QCAP];           // 8 KB
    __shared__ float          c2s[NCODES];           // 2 KB
    __shared__ unsigned long long packed[256];       // 2 KB
    __shared__ float          minA[256];             // 1 KB
    __shared__ int            qn;

    const int tid = threadIdx.x;
    const int m0  = blockIdx.x * 256;

    // stage codebook fragments (16 x b128 per thread) + c2 + init
#pragma unroll
    for (int p = 0; p < 16; ++p) {
        int idx = p * 256 + tid;                     // 0..4095
        ((float4*)CBs)[idx] = ((const float4*)cbfrag)[idx];
    }
    c2s[tid]       = c2[tid];
    c2s[tid + 256] = c2[tid + 256];
    packed[tid]    = ~0ULL;
    if (tid == 0) qn = 0;

    const int w = tid >> 6, ln = tid & 63, l15 = ln & 15, q = ln >> 4;

    // A-fragments: 4 m-tiles per wave, direct from global (L2-hot)
    bf16x8 a[4][2];
#pragma unroll
    for (int mi = 0; mi < 4; ++mi)
#pragma unroll
        for (int kk = 0; kk < 2; ++kk) {
            const float* zp = &zln[(size_t)(m0 + (w * 4 + mi) * 16 + l15) * CDIM + kk * 32 + q * 8];
            float4 v1 = *(const float4*)zp;
            float4 v2 = *(const float4*)(zp + 4);
            bf16x8 t;
            t[0] = (short)f2bf(v1.x); t[1] = (short)f2bf(v1.y);
            t[2] = (short)f2bf(v1.z); t[3] = (short)f2bf(v1.w);
            t[4] = (short)f2bf(v2.x); t[5] = (short)f2bf(v2.y);
            t[6] = (short)f2bf(v2.z); t[7] = (short)f2bf(v2.w);
            a[mi][kk] = t;
        }
    __syncthreads();

    // ---- pass 1: approx min per token ----
    float mn[4][4];
#pragma unroll
    for (int mi = 0; mi < 4; ++mi)
#pragma unroll
        for (int r = 0; r < 4; ++r) mn[mi][r] = 3.4e38f;

    for (int nt = 0; nt < 32; ++nt) {
        bf16x8 b0 = *(const bf16x8*)&CBs[((nt * 2 + 0) * 64 + ln) * 8];
        bf16x8 b1 = *(const bf16x8*)&CBs[((nt * 2 + 1) * 64 + ln) * 8];
        float c2v = c2s[nt * 16 + l15];
#pragma unroll
        for (int mi = 0; mi < 4; ++mi) {
            f32x4 acc = {0.f, 0.f, 0.f, 0.f};
            acc = __builtin_amdgcn_mfma_f32_16x16x32_bf16(a[mi][0], b0, acc, 0, 0, 0);
            acc = __builtin_amdgcn_mfma_f32_16x16x32_bf16(a[mi][1], b1, acc, 0, 0, 0);
#pragma unroll
            for (int r = 0; r < 4; ++r)
                mn[mi][r] = fminf(mn[mi][r], fmaf(-2.0f, acc[r], c2v));
        }
    }
#pragma unroll
    for (int mi = 0; mi < 4; ++mi)
#pragma unroll
        for (int r = 0; r < 4; ++r) {
            float v = mn[mi][r];
#pragma unroll
            for (int m = 1; m <= 8; m <<= 1) v = fminf(v, __shfl_xor(v, m, 64));
            if (l15 == 0) minA[(w * 4 + mi) * 16 + q * 4 + r] = v;
        }
    __syncthreads();

    float thr[4][4];
#pragma unroll
    for (int mi = 0; mi < 4; ++mi)
#pragma unroll
        for (int r = 0; r < 4; ++r)
            thr[mi][r] = minA[(w * 4 + mi) * 16 + q * 4 + r] + DELTA;

    // ---- pass 2: identical MFMAs, push candidates ----
    for (int nt = 0; nt < 32; ++nt) {
        bf16x8 b0 = *(const bf16x8*)&CBs[((nt * 2 + 0) * 64 + ln) * 8];
        bf16x8 b1 = *(const bf16x8*)&CBs[((nt * 2 + 1) * 64 + ln) * 8];
        float c2v = c2s[nt * 16 + l15];
#pragma unroll
        for (int mi = 0; mi < 4; ++mi) {
            f32x4 acc = {0.f, 0.f, 0.f, 0.f};
            acc = __builtin_amdgcn_mfma_f32_16x16x32_bf16(a[mi][0], b0, acc, 0, 0, 0);
            acc = __builtin_amdgcn_mfma_f32_16x16x32_bf16(a[mi][1], b1, acc, 0, 0, 0);
#pragma unroll
            for (int r = 0; r < 4; ++r) {
                float s = fmaf(-2.0f, acc[r], c2v);
                if (s < thr[mi][r]) {
                    int t    = (w * 4 + mi) * 16 + q * 4 + r;   // block-local token
                    int code = nt * 16 + l15;
                    int qi = atomicAdd(&qn, 1);
                    if (qi < QCAP) {
                        queue[qi] = ((unsigned int)t << 16) | (unsigned int)code;
                    } else {
                        // overflow fallback (statistically never): inline exact
                        const float* zp = &zln[(size_t)(m0 + t) * CDIM];
                        const float* cp = &cb[(size_t)code * CDIM];
                        float a0 = 0.f, a1 = 0.f, a2 = 0.f, a3 = 0.f;
#pragma unroll
                        for (int k = 0; k < CDIM; k += 4) {
                            a0 = fmaf(zp[k + 0], cp[k + 0], a0);
                            a1 = fmaf(zp[k + 1], cp[k + 1], a1);
                            a2 = fmaf(zp[k + 2], cp[k + 2], a2);
                            a3 = fmaf(zp[k + 3], cp[k + 3], a3);
                        }
                        float es = fmaf(-2.0f, (a0 + a1) + (a2 + a3), c2s[code]);
                        unsigned long long key =
                            ((unsigned long long)fkey(es) << 32) | (unsigned int)code;
                        atomicMin(&packed[t], key);
                    }
                }
            }
        }
    }
    __syncthreads();

    // ---- dense exact rescore of the queue (one entry per lane) ----
    int qn2 = qn < QCAP ? qn : QCAP;
    for (int e = tid; e < qn2; e += 256) {
        unsigned int pk = queue[e];
        int t = pk >> 16, code = pk & 0xFFFF;
        const float* zp = &zln[(size_t)(m0 + t) * CDIM];
        const float* cp = &cb[(size_t)code * CDIM];
        float a0 = 0.f, a1 = 0.f, a2 = 0.f, a3 = 0.f;
#pragma unroll
        for (int k = 0; k < CDIM; k += 4) {
            a0 = fmaf(zp[k + 0], cp[k + 0], a0);
            a1 = fmaf(zp[k + 1], cp[k + 1], a1);
            a2 = fmaf(zp[k + 2], cp[k + 2], a2);
            a3 = fmaf(zp[k + 3], cp[k + 3], a3);
        }
        float es = fmaf(-2.0f, (a0 + a1) + (a2 + a3), c2s[code]);
        unsigned long long key = ((unsigned long long)fkey(es) << 32) | (unsigned int)code;
        atomicMin(&packed[t], key);
    }
    __syncthreads();

    // ---- output: gather + write (coalesced 256B rows) ----
    const int tx = tid & 15, ty = tid >> 4;
#pragma unroll
    for (int it = 0; it < 16; ++it) {
        int tok = it * 16 + ty;
        int bi  = (int)(packed[tok] & 0xFFFFFFFFULL);
        int row = m0 + tok;
        float4 qv = *(const float4*)&cb[(size_t)bi * CDIM + tx * 4];
        *(float4*)&zq_ws [(size_t)row * CDIM + tx * 4] = qv;
        *(float4*)&zq_out[(size_t)row * CDIM + tx * 4] = qv;
        if (tx == 0) idx_out[row] = (float)bi;
    }
}

// ---------------------------------------------------------------------------
// Decoder GEMM1 (MFMA bf16) — unchanged from round 4.
// ---------------------------------------------------------------------------
__launch_bounds__(256)
__global__ void dec1_mfma(const float* __restrict__ zq, const unsigned short* __restrict__ w1t,
                          const float* __restrict__ b1, unsigned short* __restrict__ h2) {
    const int tid = threadIdx.x;
    const int wv  = tid >> 6;
    const int ln  = tid & 63;
    const int l15 = ln & 15, q = ln >> 4;
    const int mt  = blockIdx.x * 2 + (wv >> 1);
    const int nh  = wv & 1;
    const int m   = mt * 16 + l15;

    f32x4 acc[4] = {};

    for (int k0 = 0; k0 < 512; k0 += 32) {
        const float* ap = &zq[(size_t)m * 512 + k0 + q * 8];
        float4 a1 = *(const float4*)ap;
        float4 a2 = *(const float4*)(ap + 4);
        bf16x8 a;
        a[0] = (short)f2bf(a1.x); a[1] = (short)f2bf(a1.y);
        a[2] = (short)f2bf(a1.z); a[3] = (short)f2bf(a1.w);
        a[4] = (short)f2bf(a2.x); a[5] = (short)f2bf(a2.y);
        a[6] = (short)f2bf(a2.z); a[7] = (short)f2bf(a2.w);
#pragma unroll
        for (int t = 0; t < 4; ++t) {
            int n = (nh * 4 + t) * 16 + l15;
            bf16x8 b = *(const bf16x8*)&w1t[(size_t)n * 512 + k0 + q * 8];
            acc[t] = __builtin_amdgcn_mfma_f32_16x16x32_bf16(a, b, acc[t], 0, 0, 0);
        }
    }
#pragma unroll
    for (int t = 0; t < 4; ++t) {
        int col = (nh * 4 + t) * 16 + l15;
        float bb = b1[col];
#pragma unroll
        for (int r = 0; r < 4; ++r) {
            int row = mt * 16 + q * 4 + r;
            float v = fmaxf(acc[t][r] + bb, 0.0f);
            h2[(size_t)row * 128 + col] = f2bf(v);
        }
    }
}

// ---------------------------------------------------------------------------
// Decoder GEMM2 (MFMA bf16) — unchanged from round 4.
// ---------------------------------------------------------------------------
__launch_bounds__(256)
__global__ void dec2_mfma(const unsigned short* __restrict__ h2, const unsigned short* __restrict__ w2t,
                          const float* __restrict__ b2, float* __restrict__ recon) {
    const int tid = threadIdx.x;
    const int wv  = tid >> 6, ln = tid & 63;
    const int l15 = ln & 15, q = ln >> 4;
    const int mt  = blockIdx.x;
    const int m   = mt * 16 + l15;

    f32x4 acc[8] = {};
#pragma unroll
    for (int k0 = 0; k0 < 128; k0 += 32) {
        bf16x8 a = *(const bf16x8*)&h2[(size_t)m * 128 + k0 + q * 8];
#pragma unroll
        for (int t = 0; t < 8; ++t) {
            int n = (wv * 8 + t) * 16 + l15;
            bf16x8 b = *(const bf16x8*)&w2t[(size_t)n * 128 + k0 + q * 8];
            acc[t] = __builtin_amdgcn_mfma_f32_16x16x32_bf16(a, b, acc[t], 0, 0, 0);
        }
    }
#pragma unroll
    for (int t = 0; t < 8; ++t) {
        int col = (wv * 8 + t) * 16 + l15;
        float bb = b2[col];
#pragma unroll
        for (int r = 0; r < 4; ++r) {
            int row = mt * 16 + q * 4 + r;
            recon[(size_t)row * 512 + col] = acc[t][r] + bb;
        }
    }
}

// ---------------------------------------------------------------------------
extern "C" void kernel_launch(void* const* d_in, const int* in_sizes, int n_in,
                              void* d_out, int out_size, void* d_ws, size_t ws_size,
                              hipStream_t stream) {
    const float* x      = (const float*)d_in[0];
    const float* enc_w1 = (const float*)d_in[1];
    const float* enc_b1 = (const float*)d_in[2];
    const float* enc_w2 = (const float*)d_in[3];
    const float* enc_b2 = (const float*)d_in[4];
    const float* cbk    = (const float*)d_in[5];
    const float* dec_w1 = (const float*)d_in[6];
    const float* dec_b1 = (const float*)d_in[7];
    const float* dec_w2 = (const float*)d_in[8];
    const float* dec_b2 = (const float*)d_in[9];

    // outputs, all float32, concatenated flat: recon | z_q | indices
    float* out     = (float*)d_out;
    float* recon_o = out;
    float* zq_o    = out + (size_t)B_ * TD;
    float* idx_o   = out + 2 * (size_t)B_ * TD;

    // workspace: zbuf [B,512] (z_e_ln then z_q) | hbuf [B,128] | c2[512]
    //   hbuf reuse after enc2: [0,4MB) h2 bf16; +6MB: w1t|w2t|cbfrag bf16
    float* zbuf  = (float*)d_ws;
    float* hbuf  = zbuf + (size_t)B_ * TD;
    float* c2buf = hbuf + (size_t)B_ * HID;
    unsigned short* h2bf   = (unsigned short*)hbuf;
    unsigned short* w1t    = (unsigned short*)(hbuf + 1572864);
    unsigned short* w2t    = w1t + 65536;
    unsigned short* cbfrag = w2t + 65536;

    hipLaunchKernelGGL(c2_kernel, dim3(NCODES), dim3(64), 0, stream, cbk, c2buf);

    // encoder GEMM1 + ReLU: [B,512]@[512,128] -> hbuf   grid (1,256)
    hipLaunchKernelGGL((gemm_f32<true, false>), dim3(HID / 128, B_ / 64), dim3(256), 0,
                       stream, x, enc_w1, enc_b1, hbuf, HID, TD);

    // encoder GEMM2 + LN: [B,128]@[128,512] -> zbuf     grid (4,256)
    hipLaunchKernelGGL((gemm_f32<false, true>), dim3(LAT / 128, B_ / 64), dim3(256), 0,
                       stream, hbuf, enc_w2, enc_b2, zbuf, LAT, HID);

    // weight + codebook-fragment prep (after enc2 has consumed hbuf)
    hipLaunchKernelGGL(prep_kernel, dim3(640), dim3(256), 0, stream,
                       dec_w1, dec_w2, cbk, w1t, w2t, cbfrag);

    // VQ: MFMA prefilter + queued exact rescore; 512 blocks x 256 tokens
    hipLaunchKernelGGL(vq_mfma, dim3(B_ * 8 / 256), dim3(256), 0, stream,
                       zbuf, cbk, cbfrag, c2buf, zbuf, zq_o, idx_o);

    // decoder GEMM1 (MFMA): z_q -> h2 bf16              grid 512
    hipLaunchKernelGGL(dec1_mfma, dim3(512), dim3(256), 0, stream,
                       zbuf, w1t, dec_b1, h2bf);

    // decoder GEMM2 (MFMA): h2 -> recon fp32            grid 1024
    hipLaunchKernelGGL(dec2_mfma, dim3(1024), dim3(256), 0, stream,
                       h2bf, w2t, dec_b2, recon_o);
}